// Round 20
// baseline (8065.015 us; speedup 1.0000x reference)
//
#include <hip/hip_runtime.h>
#include <hip/hip_bf16.h>

// ---------------------------------------------------------------------------
// H_ACS_Encoder: B=16384, D=1024, A=4096, topk=128, T=0.7
// Outputs (flat): base_emb[B,D], weights[B,A], scores[B,A], euc_raw[B,D], euc_vec[B,D]
//
// ROUND 20 (R18/19 PASS @ ~3820us): np chain = flat ascending fp32 FMA,
// K-panels {512,512}. PERF: two-pass K-split GEMM -- pass1 writes the raw
// P0 chain to C; pass2 does in-place C = (C + P1) + bias. Bit-identical
// panel fold, but eliminates the tot[8][8] registers (140->~100 VGPR,
// 3->5 waves/SIMD) and prefetches the next tile into registers before the
// compute phase (global latency hidden under FMAs). R19 column remap kept.
//
// Scratch aliasing (no d_ws):
//   a_norm (A*D f32) -> base_emb region (base_emb written LAST)
//   q      (B*D f32) -> weights region  (dead before weights write)
//   list   (B*256)   -> euc_vec region  (dead before final norm)
// ---------------------------------------------------------------------------

#define B_ROWS 16384
#define D_DIM  1024
#define A_ATOMS 4096
#define K_TOP  128

#define KC_PANEL 512   // validated R18: AOCL/BLIS KC=512 -> panels {512,512}

// ---------------- numpy-pairwise row l2-normalize (1 wave/row, 4 rows/blk) --
__global__ __launch_bounds__(256) void rownorm_np_kernel(const float* __restrict__ src,
                                                         float* __restrict__ dst,
                                                         int nrows) {
    const int r = blockIdx.x * 4 + (threadIdx.x >> 6);
    if (r >= nrows) return;
    const int lane = threadIdx.x & 63;
    const int leaf = lane >> 3, j = lane & 7;
    const float* p = src + (size_t)r * D_DIM + leaf * 128 + j;

    float x[16];
    x[0] = p[0];
    float rs = __fmul_rn(x[0], x[0]);
#pragma unroll
    for (int i = 1; i < 16; i++) {
        x[i] = p[i * 8];
        rs = __fadd_rn(rs, __fmul_rn(x[i], x[i]));
    }
    rs = __fadd_rn(rs, __shfl_xor(rs, 1));
    rs = __fadd_rn(rs, __shfl_xor(rs, 2));
    rs = __fadd_rn(rs, __shfl_xor(rs, 4));
    rs = __fadd_rn(rs, __shfl_xor(rs, 8));
    rs = __fadd_rn(rs, __shfl_xor(rs, 16));
    rs = __fadd_rn(rs, __shfl_xor(rs, 32));

    const float nrm = fmaxf(__fsqrt_rn(rs), 1e-12f);
    float* q = dst + (size_t)r * D_DIM + leaf * 128 + j;
#pragma unroll
    for (int i = 0; i < 16; i++) q[i * 8] = __fdiv_rn(x[i], nrm);
}

// ---------------- panel-chain GEMM pass: acc = flat chain over [kbeg,kend) --
// final_pass==0 : C[m][n] = acc                      (raw P0)
// final_pass==1 : C[m][n] = (C[m][n] + acc) + bias   (fold + bias, in place)
// Thread (tx,ty): rows ty*8+{0..7}, cols tx*4+{0..3} and 64+tx*4+{0..3}.
#define GT_M 128
#define GT_N 128
#define GT_K 16

__global__ __launch_bounds__(256, 4) void gemm_pass_f32(const float* __restrict__ A,
                                                        const float* __restrict__ Bm,
                                                        const float* __restrict__ bias,
                                                        float* __restrict__ C,
                                                        int N, int Kd,
                                                        int kbeg, int kend,
                                                        int final_pass) {
    __shared__ float As[GT_K][GT_M + 4];
    __shared__ float Bs[GT_K][GT_N + 4];
    const int ntiles = N / GT_N;
    const int bn = blockIdx.x % ntiles;
    const int bm = blockIdx.x / ntiles;
    const int m0 = bm * GT_M, n0 = bn * GT_N;
    const int t = threadIdx.x;
    const int tx = t & 15, ty = t >> 4;
    const int lr = t >> 1;
    const int lk = (t & 1) * 8;

    const float* Arow = A + (size_t)(m0 + lr) * Kd + lk;
    const float* Brow = Bm + (size_t)(n0 + lr) * Kd + lk;

    float acc[8][8];
#pragma unroll
    for (int i = 0; i < 8; i++)
#pragma unroll
        for (int j = 0; j < 8; j++) acc[i][j] = 0.f;

    // prologue: stage first tile
    {
        const float4 a0 = *(const float4*)(Arow + kbeg);
        const float4 a1 = *(const float4*)(Arow + kbeg + 4);
        const float4 b0 = *(const float4*)(Brow + kbeg);
        const float4 b1 = *(const float4*)(Brow + kbeg + 4);
        As[lk + 0][lr] = a0.x; As[lk + 1][lr] = a0.y; As[lk + 2][lr] = a0.z; As[lk + 3][lr] = a0.w;
        As[lk + 4][lr] = a1.x; As[lk + 5][lr] = a1.y; As[lk + 6][lr] = a1.z; As[lk + 7][lr] = a1.w;
        Bs[lk + 0][lr] = b0.x; Bs[lk + 1][lr] = b0.y; Bs[lk + 2][lr] = b0.z; Bs[lk + 3][lr] = b0.w;
        Bs[lk + 4][lr] = b1.x; Bs[lk + 5][lr] = b1.y; Bs[lk + 6][lr] = b1.z; Bs[lk + 7][lr] = b1.w;
    }
    __syncthreads();

    for (int k0 = kbeg; k0 < kend; k0 += GT_K) {
        const bool has_next = (k0 + GT_K < kend);
        float4 na0, na1, nb0, nb1;
        if (has_next) {               // issue next-tile loads BEFORE compute
            na0 = *(const float4*)(Arow + k0 + GT_K);
            na1 = *(const float4*)(Arow + k0 + GT_K + 4);
            nb0 = *(const float4*)(Brow + k0 + GT_K);
            nb1 = *(const float4*)(Brow + k0 + GT_K + 4);
        }
#pragma unroll
        for (int k = 0; k < GT_K; k++) {   // ascending k within panel
            const float4 av0 = *(const float4*)&As[k][ty * 8];
            const float4 av1 = *(const float4*)&As[k][ty * 8 + 4];
            const float4 bv0 = *(const float4*)&Bs[k][tx * 4];
            const float4 bv1 = *(const float4*)&Bs[k][64 + tx * 4];
            const float af[8] = {av0.x, av0.y, av0.z, av0.w, av1.x, av1.y, av1.z, av1.w};
            const float bf[8] = {bv0.x, bv0.y, bv0.z, bv0.w, bv1.x, bv1.y, bv1.z, bv1.w};
#pragma unroll
            for (int i = 0; i < 8; i++)
#pragma unroll
                for (int j = 0; j < 8; j++)
                    acc[i][j] = __fmaf_rn(af[i], bf[j], acc[i][j]);
        }
        if (has_next) {
            __syncthreads();   // all reads of current tile complete
            As[lk + 0][lr] = na0.x; As[lk + 1][lr] = na0.y; As[lk + 2][lr] = na0.z; As[lk + 3][lr] = na0.w;
            As[lk + 4][lr] = na1.x; As[lk + 5][lr] = na1.y; As[lk + 6][lr] = na1.z; As[lk + 7][lr] = na1.w;
            Bs[lk + 0][lr] = nb0.x; Bs[lk + 1][lr] = nb0.y; Bs[lk + 2][lr] = nb0.z; Bs[lk + 3][lr] = nb0.w;
            Bs[lk + 4][lr] = nb1.x; Bs[lk + 5][lr] = nb1.y; Bs[lk + 6][lr] = nb1.z; Bs[lk + 7][lr] = nb1.w;
            __syncthreads();
        }
    }

    if (!final_pass) {
        // raw P0 chain out
#pragma unroll
        for (int i = 0; i < 8; i++) {
            const size_t row = (size_t)(m0 + ty * 8 + i);
            float4 c0, c1;
            c0.x = acc[i][0]; c0.y = acc[i][1]; c0.z = acc[i][2]; c0.w = acc[i][3];
            c1.x = acc[i][4]; c1.y = acc[i][5]; c1.z = acc[i][6]; c1.w = acc[i][7];
            *(float4*)(C + row * (size_t)N + n0 + tx * 4) = c0;
            *(float4*)(C + row * (size_t)N + n0 + 64 + tx * 4) = c1;
        }
    } else {
        float bj[8];
#pragma unroll
        for (int j = 0; j < 4; j++) {
            bj[j]     = bias ? bias[n0 + tx * 4 + j]      : 0.f;
            bj[4 + j] = bias ? bias[n0 + 64 + tx * 4 + j] : 0.f;
        }
#pragma unroll
        for (int i = 0; i < 8; i++) {
            const size_t row = (size_t)(m0 + ty * 8 + i);
            float* cp0 = C + row * (size_t)N + n0 + tx * 4;
            float* cp1 = C + row * (size_t)N + n0 + 64 + tx * 4;
            const float4 p0a = *(const float4*)cp0;
            const float4 p0b = *(const float4*)cp1;
            float4 c0, c1;
            c0.x = __fadd_rn(__fadd_rn(p0a.x, acc[i][0]), bj[0]);
            c0.y = __fadd_rn(__fadd_rn(p0a.y, acc[i][1]), bj[1]);
            c0.z = __fadd_rn(__fadd_rn(p0a.z, acc[i][2]), bj[2]);
            c0.w = __fadd_rn(__fadd_rn(p0a.w, acc[i][3]), bj[3]);
            c1.x = __fadd_rn(__fadd_rn(p0b.x, acc[i][4]), bj[4]);
            c1.y = __fadd_rn(__fadd_rn(p0b.y, acc[i][5]), bj[5]);
            c1.z = __fadd_rn(__fadd_rn(p0b.z, acc[i][6]), bj[6]);
            c1.w = __fadd_rn(__fadd_rn(p0b.w, acc[i][7]), bj[7]);
            *(float4*)cp0 = c0;
            *(float4*)cp1 = c1;
        }
    }
}

// ---------------- exact fp32 top-128 (ties -> lowest index) + softmax ------
__device__ __forceinline__ unsigned f2key(float f) {
    unsigned u = __float_as_uint(f);
    return (u & 0x80000000u) ? ~u : (u | 0x80000000u);
}

__global__ __launch_bounds__(256) void topk32_kernel(const float* __restrict__ scores,
                                                     float* __restrict__ weights,
                                                     float* __restrict__ list) {
    __shared__ float s[A_ATOMS];
    __shared__ unsigned hist[256];
    __shared__ int scanb[256];
    __shared__ float fred[8];
    __shared__ unsigned ubc[4];
    __shared__ unsigned char selb[A_ATOMS];

    const int r = blockIdx.x;
    const int t = threadIdx.x;
    const int lane = t & 63, wid = t >> 6;
    const float* srow = scores + (size_t)r * A_ATOMS;

#pragma unroll
    for (int c = 0; c < 4; c++) {
        const int i = c * 1024 + t * 4;
        *(float4*)(s + i) = *(const float4*)(srow + i);
    }
    __syncthreads();

    // 4-pass radix select (8-bit digits, MSB first) for the 128th largest
    unsigned prefix = 0, remaining = K_TOP;
    for (int shift = 24; shift >= 0; shift -= 8) {
        hist[t] = 0u;
        __syncthreads();
        for (int j = 0; j < 16; j++) {
            const unsigned u = f2key(s[t * 16 + j]);
            const bool isc = (shift == 24) || ((u >> (shift + 8)) == (prefix >> (shift + 8)));
            if (isc) atomicAdd(&hist[(u >> shift) & 255u], 1u);
        }
        __syncthreads();
        scanb[t] = (int)hist[t];
        __syncthreads();
        for (int off = 1; off < 256; off <<= 1) {   // suffix scan
            const int add = (t + off < 256) ? scanb[t + off] : 0;
            __syncthreads();
            scanb[t] += add;
            __syncthreads();
        }
        const int sfx = scanb[t];
        const int sfxn = (t < 255) ? scanb[t + 1] : 0;
        if (sfx >= (int)remaining && sfxn < (int)remaining) {
            ubc[0] = prefix | ((unsigned)t << shift);
            ubc[1] = remaining - (unsigned)sfxn;
        }
        __syncthreads();
        prefix = ubc[0];
        remaining = ubc[1];
    }
    const unsigned Tkey = prefix;
    const int need = (int)remaining;   // #equal-to-threshold to include

    // strict winners; equals -> lowest `need` indices (stable)
    int myeq = 0;
    for (int j = 0; j < 16; j++) {
        const int i = t * 16 + j;
        const unsigned u = f2key(s[i]);
        selb[i] = (u > Tkey) ? 1 : 0;
        myeq += (u == Tkey) ? 1 : 0;
    }
    scanb[t] = myeq;
    __syncthreads();
    for (int off = 1; off < 256; off <<= 1) {   // inclusive ascending scan
        const int v = scanb[t];
        const int add = (t >= off) ? scanb[t - off] : 0;
        __syncthreads();
        scanb[t] = v + add;
        __syncthreads();
    }
    int epos = scanb[t] - myeq;
    for (int j = 0; j < 16; j++) {
        const int i = t * 16 + j;
        if (f2key(s[i]) == Tkey) { if (epos < need) selb[i] = 1; epos++; }
    }
    __syncthreads();

    // fp32 softmax over selected
    float zmax = -3.4e38f;
    for (int j = 0; j < 16; j++) {
        const int i = t * 16 + j;
        if (selb[i]) zmax = fmaxf(zmax, __fdiv_rn(s[i], 0.7f));
    }
    for (int o = 32; o > 0; o >>= 1) zmax = fmaxf(zmax, __shfl_down(zmax, o, 64));
    if (lane == 0) fred[wid] = zmax;
    __syncthreads();
    if (t == 0) fred[4] = fmaxf(fmaxf(fred[0], fred[1]), fmaxf(fred[2], fred[3]));
    __syncthreads();
    const float zm = fred[4];

    float esum = 0.f;
    int selcnt = 0;
    for (int j = 0; j < 16; j++) {
        const int i = t * 16 + j;
        if (selb[i]) { esum += expf(__fdiv_rn(s[i], 0.7f) - zm); selcnt++; }
    }
    for (int o = 32; o > 0; o >>= 1) esum += __shfl_down(esum, o, 64);
    if (lane == 0) fred[wid] = esum;
    __syncthreads();
    if (t == 0) fred[4] = fred[0] + fred[1] + fred[2] + fred[3];
    __syncthreads();
    const float S = fred[4];

    // dense weights row
    float* wrow = weights + (size_t)r * A_ATOMS;
#pragma unroll
    for (int c = 0; c < 4; c++) {
        const int i = c * 1024 + t * 4;
        float4 w4;
        float wv[4];
#pragma unroll
        for (int j = 0; j < 4; j++) {
            wv[j] = selb[i + j]
                ? __fdiv_rn(expf(__fdiv_rn(s[i + j], 0.7f) - zm), S)
                : 0.f;
        }
        w4.x = wv[0]; w4.y = wv[1]; w4.z = wv[2]; w4.w = wv[3];
        *(float4*)(wrow + i) = w4;
    }

    // compact (idx, w) list in ascending atom-index order (for euc chain)
    __syncthreads();
    scanb[t] = selcnt;
    __syncthreads();
    for (int off = 1; off < 256; off <<= 1) {
        const int v = scanb[t];
        const int add = (t >= off) ? scanb[t - off] : 0;
        __syncthreads();
        scanb[t] = v + add;
        __syncthreads();
    }
    int pos = scanb[t] - selcnt;
    int* li = (int*)(list + (size_t)r * 256);
    float* lw = list + (size_t)r * 256 + 128;
    for (int j = 0; j < 16; j++) {
        const int i = t * 16 + j;
        if (selb[i]) {
            const float w = __fdiv_rn(expf(__fdiv_rn(s[i], 0.7f) - zm), S);
            if (pos < K_TOP) { li[pos] = i; lw[pos] = w; }
            pos++;
        }
    }
}

// ---------------- euc_raw[r] = sum_j w_j * atoms[idx_j] (ascending idx) -----
__global__ __launch_bounds__(256) void euc_gather_kernel(const float* __restrict__ atoms,
                                                         const float* __restrict__ list,
                                                         float* __restrict__ euc) {
    __shared__ int sidx[K_TOP];
    __shared__ float sw[K_TOP];
    const int r = blockIdx.x, t = threadIdx.x;
    if (t < K_TOP) {
        sidx[t] = ((const int*)list)[(size_t)r * 256 + t];
        sw[t] = list[(size_t)r * 256 + 128 + t];
    }
    __syncthreads();
    const float4* A4 = (const float4*)atoms;
    float4 acc = {0.f, 0.f, 0.f, 0.f};
#pragma unroll 4
    for (int j = 0; j < K_TOP; j++) {      // ascending atom index
        const float w = sw[j];
        const float4 a = A4[(size_t)sidx[j] * 256 + t];
        acc.x = __fmaf_rn(w, a.x, acc.x);
        acc.y = __fmaf_rn(w, a.y, acc.y);
        acc.z = __fmaf_rn(w, a.z, acc.z);
        acc.w = __fmaf_rn(w, a.w, acc.w);
    }
    ((float4*)euc)[(size_t)r * 256 + t] = acc;
}

// ---------------------------------------------------------------------------
extern "C" void kernel_launch(void* const* d_in, const int* in_sizes, int n_in,
                              void* d_out, int out_size, void* d_ws, size_t ws_size,
                              hipStream_t stream) {
    const float* base_raw = (const float*)d_in[0];
    const float* W        = (const float*)d_in[1];
    const float* bvec     = (const float*)d_in[2];
    const float* atoms    = (const float*)d_in[3];
    float* out = (float*)d_out;

    const size_t BD = (size_t)B_ROWS * D_DIM;   // 16,777,216
    const size_t BA = (size_t)B_ROWS * A_ATOMS; // 67,108,864
    float* base_emb = out;
    float* weights  = out + BD;
    float* scores   = out + BD + BA;
    float* euc_raw  = out + BD + 2 * BA;
    float* euc_vec  = out + 2 * BD + 2 * BA;

    float* a_norm = base_emb;  // scratch: A*D = 4.2M floats <= BD
    float* q      = weights;   // scratch: B*D floats <= BA
    float* list   = euc_vec;   // scratch: B*256 floats <= BD

    const int grid_q = (B_ROWS / GT_M) * (D_DIM / GT_N);
    const int grid_s = (B_ROWS / GT_M) * (A_ATOMS / GT_N);

    // 1. a_norm = l2norm_np(atoms)
    rownorm_np_kernel<<<A_ATOMS / 4, 256, 0, stream>>>(atoms, a_norm, A_ATOMS);
    // 2. q_raw = base_raw @ W^T + b   (two-pass {512,512} flat chains)
    gemm_pass_f32<<<grid_q, 256, 0, stream>>>(base_raw, W, nullptr, q,
                                              D_DIM, D_DIM, 0, KC_PANEL, 0);
    gemm_pass_f32<<<grid_q, 256, 0, stream>>>(base_raw, W, bvec, q,
                                              D_DIM, D_DIM, KC_PANEL, D_DIM, 1);
    // 3. q = l2norm_np(q_raw) in place
    rownorm_np_kernel<<<B_ROWS / 4, 256, 0, stream>>>(q, q, B_ROWS);
    // 4. scores = q @ a_norm^T        (two-pass {512,512} flat chains)
    gemm_pass_f32<<<grid_s, 256, 0, stream>>>(q, a_norm, nullptr, scores,
                                              A_ATOMS, D_DIM, 0, KC_PANEL, 0);
    gemm_pass_f32<<<grid_s, 256, 0, stream>>>(q, a_norm, nullptr, scores,
                                              A_ATOMS, D_DIM, KC_PANEL, D_DIM, 1);
    // 5. exact fp32 top-128 (stable ties) + fp32 softmax -> weights + list
    topk32_kernel<<<B_ROWS, 256, 0, stream>>>(scores, weights, list);
    // 6. euc_raw = weights @ atoms (sparse gather, ascending index chain)
    euc_gather_kernel<<<B_ROWS, 256, 0, stream>>>(atoms, list, euc_raw);
    // 7. euc_vec = l2norm_np(euc_raw)
    rownorm_np_kernel<<<B_ROWS / 4, 256, 0, stream>>>(euc_raw, euc_vec, B_ROWS);
    // 8. base_emb = l2norm_np(base_raw)  (last: frees a_norm aliasing)
    rownorm_np_kernel<<<B_ROWS / 4, 256, 0, stream>>>(base_raw, base_emb, B_ROWS);
}

// Round 21
// 3227.549 us; speedup vs baseline: 2.4988x; 2.4988x over previous
//
#include <hip/hip_runtime.h>
#include <hip/hip_bf16.h>

// ---------------------------------------------------------------------------
// H_ACS_Encoder: B=16384, D=1024, A=4096, topk=128, T=0.7
// Outputs (flat): base_emb[B,D], weights[B,A], scores[B,A], euc_raw[B,D], euc_vec[B,D]
//
// ROUND 21: R20's forced __launch_bounds__(256,4) capped VGPR at 64 ->
// acc[8][8] spilled to scratch (hbm_bytes 0.67GB -> 13.4GB, VALUBusy 20%,
// 2x slower). SAME two-pass {512,512} bit-exact structure + register
// prefetch, but natural register allocation (launch_bounds(256)): ~110 VGPR,
// 4 waves/SIMD, no spill.
//
// Scratch aliasing (no d_ws):
//   a_norm (A*D f32) -> base_emb region (base_emb written LAST)
//   q      (B*D f32) -> weights region  (dead before weights write)
//   list   (B*256)   -> euc_vec region  (dead before final norm)
// ---------------------------------------------------------------------------

#define B_ROWS 16384
#define D_DIM  1024
#define A_ATOMS 4096
#define K_TOP  128

#define KC_PANEL 512   // validated R18: AOCL/BLIS KC=512 -> panels {512,512}

// ---------------- numpy-pairwise row l2-normalize (1 wave/row, 4 rows/blk) --
__global__ __launch_bounds__(256) void rownorm_np_kernel(const float* __restrict__ src,
                                                         float* __restrict__ dst,
                                                         int nrows) {
    const int r = blockIdx.x * 4 + (threadIdx.x >> 6);
    if (r >= nrows) return;
    const int lane = threadIdx.x & 63;
    const int leaf = lane >> 3, j = lane & 7;
    const float* p = src + (size_t)r * D_DIM + leaf * 128 + j;

    float x[16];
    x[0] = p[0];
    float rs = __fmul_rn(x[0], x[0]);
#pragma unroll
    for (int i = 1; i < 16; i++) {
        x[i] = p[i * 8];
        rs = __fadd_rn(rs, __fmul_rn(x[i], x[i]));
    }
    rs = __fadd_rn(rs, __shfl_xor(rs, 1));
    rs = __fadd_rn(rs, __shfl_xor(rs, 2));
    rs = __fadd_rn(rs, __shfl_xor(rs, 4));
    rs = __fadd_rn(rs, __shfl_xor(rs, 8));
    rs = __fadd_rn(rs, __shfl_xor(rs, 16));
    rs = __fadd_rn(rs, __shfl_xor(rs, 32));

    const float nrm = fmaxf(__fsqrt_rn(rs), 1e-12f);
    float* q = dst + (size_t)r * D_DIM + leaf * 128 + j;
#pragma unroll
    for (int i = 0; i < 16; i++) q[i * 8] = __fdiv_rn(x[i], nrm);
}

// ---------------- panel-chain GEMM pass: acc = flat chain over [kbeg,kend) --
// final_pass==0 : C[m][n] = acc                      (raw P0)
// final_pass==1 : C[m][n] = (C[m][n] + acc) + bias   (fold + bias, in place)
// Thread (tx,ty): rows ty*8+{0..7}, cols tx*4+{0..3} and 64+tx*4+{0..3}.
#define GT_M 128
#define GT_N 128
#define GT_K 16

__global__ __launch_bounds__(256) void gemm_pass_f32(const float* __restrict__ A,
                                                     const float* __restrict__ Bm,
                                                     const float* __restrict__ bias,
                                                     float* __restrict__ C,
                                                     int N, int Kd,
                                                     int kbeg, int kend,
                                                     int final_pass) {
    __shared__ float As[GT_K][GT_M + 4];
    __shared__ float Bs[GT_K][GT_N + 4];
    const int ntiles = N / GT_N;
    const int bn = blockIdx.x % ntiles;
    const int bm = blockIdx.x / ntiles;
    const int m0 = bm * GT_M, n0 = bn * GT_N;
    const int t = threadIdx.x;
    const int tx = t & 15, ty = t >> 4;
    const int lr = t >> 1;
    const int lk = (t & 1) * 8;

    const float* Arow = A + (size_t)(m0 + lr) * Kd + lk;
    const float* Brow = Bm + (size_t)(n0 + lr) * Kd + lk;

    float acc[8][8];
#pragma unroll
    for (int i = 0; i < 8; i++)
#pragma unroll
        for (int j = 0; j < 8; j++) acc[i][j] = 0.f;

    // prologue: stage first tile
    {
        const float4 a0 = *(const float4*)(Arow + kbeg);
        const float4 a1 = *(const float4*)(Arow + kbeg + 4);
        const float4 b0 = *(const float4*)(Brow + kbeg);
        const float4 b1 = *(const float4*)(Brow + kbeg + 4);
        As[lk + 0][lr] = a0.x; As[lk + 1][lr] = a0.y; As[lk + 2][lr] = a0.z; As[lk + 3][lr] = a0.w;
        As[lk + 4][lr] = a1.x; As[lk + 5][lr] = a1.y; As[lk + 6][lr] = a1.z; As[lk + 7][lr] = a1.w;
        Bs[lk + 0][lr] = b0.x; Bs[lk + 1][lr] = b0.y; Bs[lk + 2][lr] = b0.z; Bs[lk + 3][lr] = b0.w;
        Bs[lk + 4][lr] = b1.x; Bs[lk + 5][lr] = b1.y; Bs[lk + 6][lr] = b1.z; Bs[lk + 7][lr] = b1.w;
    }
    __syncthreads();

    for (int k0 = kbeg; k0 < kend; k0 += GT_K) {
        const bool has_next = (k0 + GT_K < kend);
        float4 na0, na1, nb0, nb1;
        if (has_next) {               // issue next-tile loads BEFORE compute
            na0 = *(const float4*)(Arow + k0 + GT_K);
            na1 = *(const float4*)(Arow + k0 + GT_K + 4);
            nb0 = *(const float4*)(Brow + k0 + GT_K);
            nb1 = *(const float4*)(Brow + k0 + GT_K + 4);
        }
#pragma unroll
        for (int k = 0; k < GT_K; k++) {   // ascending k within panel
            const float4 av0 = *(const float4*)&As[k][ty * 8];
            const float4 av1 = *(const float4*)&As[k][ty * 8 + 4];
            const float4 bv0 = *(const float4*)&Bs[k][tx * 4];
            const float4 bv1 = *(const float4*)&Bs[k][64 + tx * 4];
            const float af[8] = {av0.x, av0.y, av0.z, av0.w, av1.x, av1.y, av1.z, av1.w};
            const float bf[8] = {bv0.x, bv0.y, bv0.z, bv0.w, bv1.x, bv1.y, bv1.z, bv1.w};
#pragma unroll
            for (int i = 0; i < 8; i++)
#pragma unroll
                for (int j = 0; j < 8; j++)
                    acc[i][j] = __fmaf_rn(af[i], bf[j], acc[i][j]);
        }
        if (has_next) {
            __syncthreads();   // all reads of current tile complete
            As[lk + 0][lr] = na0.x; As[lk + 1][lr] = na0.y; As[lk + 2][lr] = na0.z; As[lk + 3][lr] = na0.w;
            As[lk + 4][lr] = na1.x; As[lk + 5][lr] = na1.y; As[lk + 6][lr] = na1.z; As[lk + 7][lr] = na1.w;
            Bs[lk + 0][lr] = nb0.x; Bs[lk + 1][lr] = nb0.y; Bs[lk + 2][lr] = nb0.z; Bs[lk + 3][lr] = nb0.w;
            Bs[lk + 4][lr] = nb1.x; Bs[lk + 5][lr] = nb1.y; Bs[lk + 6][lr] = nb1.z; Bs[lk + 7][lr] = nb1.w;
            __syncthreads();
        }
    }

    if (!final_pass) {
        // raw P0 chain out
#pragma unroll
        for (int i = 0; i < 8; i++) {
            const size_t row = (size_t)(m0 + ty * 8 + i);
            float4 c0, c1;
            c0.x = acc[i][0]; c0.y = acc[i][1]; c0.z = acc[i][2]; c0.w = acc[i][3];
            c1.x = acc[i][4]; c1.y = acc[i][5]; c1.z = acc[i][6]; c1.w = acc[i][7];
            *(float4*)(C + row * (size_t)N + n0 + tx * 4) = c0;
            *(float4*)(C + row * (size_t)N + n0 + 64 + tx * 4) = c1;
        }
    } else {
        float bj[8];
#pragma unroll
        for (int j = 0; j < 4; j++) {
            bj[j]     = bias ? bias[n0 + tx * 4 + j]      : 0.f;
            bj[4 + j] = bias ? bias[n0 + 64 + tx * 4 + j] : 0.f;
        }
#pragma unroll
        for (int i = 0; i < 8; i++) {
            const size_t row = (size_t)(m0 + ty * 8 + i);
            float* cp0 = C + row * (size_t)N + n0 + tx * 4;
            float* cp1 = C + row * (size_t)N + n0 + 64 + tx * 4;
            const float4 p0a = *(const float4*)cp0;
            const float4 p0b = *(const float4*)cp1;
            float4 c0, c1;
            c0.x = __fadd_rn(__fadd_rn(p0a.x, acc[i][0]), bj[0]);
            c0.y = __fadd_rn(__fadd_rn(p0a.y, acc[i][1]), bj[1]);
            c0.z = __fadd_rn(__fadd_rn(p0a.z, acc[i][2]), bj[2]);
            c0.w = __fadd_rn(__fadd_rn(p0a.w, acc[i][3]), bj[3]);
            c1.x = __fadd_rn(__fadd_rn(p0b.x, acc[i][4]), bj[4]);
            c1.y = __fadd_rn(__fadd_rn(p0b.y, acc[i][5]), bj[5]);
            c1.z = __fadd_rn(__fadd_rn(p0b.z, acc[i][6]), bj[6]);
            c1.w = __fadd_rn(__fadd_rn(p0b.w, acc[i][7]), bj[7]);
            *(float4*)cp0 = c0;
            *(float4*)cp1 = c1;
        }
    }
}

// ---------------- exact fp32 top-128 (ties -> lowest index) + softmax ------
__device__ __forceinline__ unsigned f2key(float f) {
    unsigned u = __float_as_uint(f);
    return (u & 0x80000000u) ? ~u : (u | 0x80000000u);
}

__global__ __launch_bounds__(256) void topk32_kernel(const float* __restrict__ scores,
                                                     float* __restrict__ weights,
                                                     float* __restrict__ list) {
    __shared__ float s[A_ATOMS];
    __shared__ unsigned hist[256];
    __shared__ int scanb[256];
    __shared__ float fred[8];
    __shared__ unsigned ubc[4];
    __shared__ unsigned char selb[A_ATOMS];

    const int r = blockIdx.x;
    const int t = threadIdx.x;
    const int lane = t & 63, wid = t >> 6;
    const float* srow = scores + (size_t)r * A_ATOMS;

#pragma unroll
    for (int c = 0; c < 4; c++) {
        const int i = c * 1024 + t * 4;
        *(float4*)(s + i) = *(const float4*)(srow + i);
    }
    __syncthreads();

    // 4-pass radix select (8-bit digits, MSB first) for the 128th largest
    unsigned prefix = 0, remaining = K_TOP;
    for (int shift = 24; shift >= 0; shift -= 8) {
        hist[t] = 0u;
        __syncthreads();
        for (int j = 0; j < 16; j++) {
            const unsigned u = f2key(s[t * 16 + j]);
            const bool isc = (shift == 24) || ((u >> (shift + 8)) == (prefix >> (shift + 8)));
            if (isc) atomicAdd(&hist[(u >> shift) & 255u], 1u);
        }
        __syncthreads();
        scanb[t] = (int)hist[t];
        __syncthreads();
        for (int off = 1; off < 256; off <<= 1) {   // suffix scan
            const int add = (t + off < 256) ? scanb[t + off] : 0;
            __syncthreads();
            scanb[t] += add;
            __syncthreads();
        }
        const int sfx = scanb[t];
        const int sfxn = (t < 255) ? scanb[t + 1] : 0;
        if (sfx >= (int)remaining && sfxn < (int)remaining) {
            ubc[0] = prefix | ((unsigned)t << shift);
            ubc[1] = remaining - (unsigned)sfxn;
        }
        __syncthreads();
        prefix = ubc[0];
        remaining = ubc[1];
    }
    const unsigned Tkey = prefix;
    const int need = (int)remaining;   // #equal-to-threshold to include

    // strict winners; equals -> lowest `need` indices (stable)
    int myeq = 0;
    for (int j = 0; j < 16; j++) {
        const int i = t * 16 + j;
        const unsigned u = f2key(s[i]);
        selb[i] = (u > Tkey) ? 1 : 0;
        myeq += (u == Tkey) ? 1 : 0;
    }
    scanb[t] = myeq;
    __syncthreads();
    for (int off = 1; off < 256; off <<= 1) {   // inclusive ascending scan
        const int v = scanb[t];
        const int add = (t >= off) ? scanb[t - off] : 0;
        __syncthreads();
        scanb[t] = v + add;
        __syncthreads();
    }
    int epos = scanb[t] - myeq;
    for (int j = 0; j < 16; j++) {
        const int i = t * 16 + j;
        if (f2key(s[i]) == Tkey) { if (epos < need) selb[i] = 1; epos++; }
    }
    __syncthreads();

    // fp32 softmax over selected
    float zmax = -3.4e38f;
    for (int j = 0; j < 16; j++) {
        const int i = t * 16 + j;
        if (selb[i]) zmax = fmaxf(zmax, __fdiv_rn(s[i], 0.7f));
    }
    for (int o = 32; o > 0; o >>= 1) zmax = fmaxf(zmax, __shfl_down(zmax, o, 64));
    if (lane == 0) fred[wid] = zmax;
    __syncthreads();
    if (t == 0) fred[4] = fmaxf(fmaxf(fred[0], fred[1]), fmaxf(fred[2], fred[3]));
    __syncthreads();
    const float zm = fred[4];

    float esum = 0.f;
    int selcnt = 0;
    for (int j = 0; j < 16; j++) {
        const int i = t * 16 + j;
        if (selb[i]) { esum += expf(__fdiv_rn(s[i], 0.7f) - zm); selcnt++; }
    }
    for (int o = 32; o > 0; o >>= 1) esum += __shfl_down(esum, o, 64);
    if (lane == 0) fred[wid] = esum;
    __syncthreads();
    if (t == 0) fred[4] = fred[0] + fred[1] + fred[2] + fred[3];
    __syncthreads();
    const float S = fred[4];

    // dense weights row
    float* wrow = weights + (size_t)r * A_ATOMS;
#pragma unroll
    for (int c = 0; c < 4; c++) {
        const int i = c * 1024 + t * 4;
        float4 w4;
        float wv[4];
#pragma unroll
        for (int j = 0; j < 4; j++) {
            wv[j] = selb[i + j]
                ? __fdiv_rn(expf(__fdiv_rn(s[i + j], 0.7f) - zm), S)
                : 0.f;
        }
        w4.x = wv[0]; w4.y = wv[1]; w4.z = wv[2]; w4.w = wv[3];
        *(float4*)(wrow + i) = w4;
    }

    // compact (idx, w) list in ascending atom-index order (for euc chain)
    __syncthreads();
    scanb[t] = selcnt;
    __syncthreads();
    for (int off = 1; off < 256; off <<= 1) {
        const int v = scanb[t];
        const int add = (t >= off) ? scanb[t - off] : 0;
        __syncthreads();
        scanb[t] = v + add;
        __syncthreads();
    }
    int pos = scanb[t] - selcnt;
    int* li = (int*)(list + (size_t)r * 256);
    float* lw = list + (size_t)r * 256 + 128;
    for (int j = 0; j < 16; j++) {
        const int i = t * 16 + j;
        if (selb[i]) {
            const float w = __fdiv_rn(expf(__fdiv_rn(s[i], 0.7f) - zm), S);
            if (pos < K_TOP) { li[pos] = i; lw[pos] = w; }
            pos++;
        }
    }
}

// ---------------- euc_raw[r] = sum_j w_j * atoms[idx_j] (ascending idx) -----
__global__ __launch_bounds__(256) void euc_gather_kernel(const float* __restrict__ atoms,
                                                         const float* __restrict__ list,
                                                         float* __restrict__ euc) {
    __shared__ int sidx[K_TOP];
    __shared__ float sw[K_TOP];
    const int r = blockIdx.x, t = threadIdx.x;
    if (t < K_TOP) {
        sidx[t] = ((const int*)list)[(size_t)r * 256 + t];
        sw[t] = list[(size_t)r * 256 + 128 + t];
    }
    __syncthreads();
    const float4* A4 = (const float4*)atoms;
    float4 acc = {0.f, 0.f, 0.f, 0.f};
#pragma unroll 4
    for (int j = 0; j < K_TOP; j++) {      // ascending atom index
        const float w = sw[j];
        const float4 a = A4[(size_t)sidx[j] * 256 + t];
        acc.x = __fmaf_rn(w, a.x, acc.x);
        acc.y = __fmaf_rn(w, a.y, acc.y);
        acc.z = __fmaf_rn(w, a.z, acc.z);
        acc.w = __fmaf_rn(w, a.w, acc.w);
    }
    ((float4*)euc)[(size_t)r * 256 + t] = acc;
}

// ---------------------------------------------------------------------------
extern "C" void kernel_launch(void* const* d_in, const int* in_sizes, int n_in,
                              void* d_out, int out_size, void* d_ws, size_t ws_size,
                              hipStream_t stream) {
    const float* base_raw = (const float*)d_in[0];
    const float* W        = (const float*)d_in[1];
    const float* bvec     = (const float*)d_in[2];
    const float* atoms    = (const float*)d_in[3];
    float* out = (float*)d_out;

    const size_t BD = (size_t)B_ROWS * D_DIM;   // 16,777,216
    const size_t BA = (size_t)B_ROWS * A_ATOMS; // 67,108,864
    float* base_emb = out;
    float* weights  = out + BD;
    float* scores   = out + BD + BA;
    float* euc_raw  = out + BD + 2 * BA;
    float* euc_vec  = out + 2 * BD + 2 * BA;

    float* a_norm = base_emb;  // scratch: A*D = 4.2M floats <= BD
    float* q      = weights;   // scratch: B*D floats <= BA
    float* list   = euc_vec;   // scratch: B*256 floats <= BD

    const int grid_q = (B_ROWS / GT_M) * (D_DIM / GT_N);
    const int grid_s = (B_ROWS / GT_M) * (A_ATOMS / GT_N);

    // 1. a_norm = l2norm_np(atoms)
    rownorm_np_kernel<<<A_ATOMS / 4, 256, 0, stream>>>(atoms, a_norm, A_ATOMS);
    // 2. q_raw = base_raw @ W^T + b   (two-pass {512,512} flat chains)
    gemm_pass_f32<<<grid_q, 256, 0, stream>>>(base_raw, W, nullptr, q,
                                              D_DIM, D_DIM, 0, KC_PANEL, 0);
    gemm_pass_f32<<<grid_q, 256, 0, stream>>>(base_raw, W, bvec, q,
                                              D_DIM, D_DIM, KC_PANEL, D_DIM, 1);
    // 3. q = l2norm_np(q_raw) in place
    rownorm_np_kernel<<<B_ROWS / 4, 256, 0, stream>>>(q, q, B_ROWS);
    // 4. scores = q @ a_norm^T        (two-pass {512,512} flat chains)
    gemm_pass_f32<<<grid_s, 256, 0, stream>>>(q, a_norm, nullptr, scores,
                                              A_ATOMS, D_DIM, 0, KC_PANEL, 0);
    gemm_pass_f32<<<grid_s, 256, 0, stream>>>(q, a_norm, nullptr, scores,
                                              A_ATOMS, D_DIM, KC_PANEL, D_DIM, 1);
    // 5. exact fp32 top-128 (stable ties) + fp32 softmax -> weights + list
    topk32_kernel<<<B_ROWS, 256, 0, stream>>>(scores, weights, list);
    // 6. euc_raw = weights @ atoms (sparse gather, ascending index chain)
    euc_gather_kernel<<<B_ROWS, 256, 0, stream>>>(atoms, list, euc_raw);
    // 7. euc_vec = l2norm_np(euc_raw)
    rownorm_np_kernel<<<B_ROWS / 4, 256, 0, stream>>>(euc_raw, euc_vec, B_ROWS);
    // 8. base_emb = l2norm_np(base_raw)  (last: frees a_norm aliasing)
    rownorm_np_kernel<<<B_ROWS / 4, 256, 0, stream>>>(base_raw, base_emb, B_ROWS);
}

// Round 22
// 3119.772 us; speedup vs baseline: 2.5851x; 1.0345x over previous
//
#include <hip/hip_runtime.h>
#include <hip/hip_bf16.h>

// ---------------------------------------------------------------------------
// H_ACS_Encoder: B=16384, D=1024, A=4096, topk=128, T=0.7
// Outputs (flat): base_emb[B,D], weights[B,A], scores[B,A], euc_raw[B,D], euc_vec[B,D]
//
// ROUND 22 (baseline R21 PASS @ 3227us): np chain = flat ascending fp32 FMA,
// K-panels {512,512} (two-pass, validated). This round:
//  (a) GEMM: 128x256 tile, per-thread 8x16 (FMA/LDS-read 16->21.3), LDS
//      double-buffer (1 barrier/iter). Bit-exact per-element chains.
//  (b) topk: register-resident keys (same t*16 mapping -> identical tie
//      order), per-wave histogram copies, shfl wave scans (~16 barriers).
//
// Scratch aliasing (no d_ws):
//   a_norm (A*D f32) -> base_emb region (base_emb written LAST)
//   q      (B*D f32) -> weights region  (dead before weights write)
//   list   (B*256)   -> euc_vec region  (dead before final norm)
// ---------------------------------------------------------------------------

#define B_ROWS 16384
#define D_DIM  1024
#define A_ATOMS 4096
#define K_TOP  128

#define KC_PANEL 512   // validated R18: panels {512,512}

// ---------------- numpy-pairwise row l2-normalize (1 wave/row, 4 rows/blk) --
__global__ __launch_bounds__(256) void rownorm_np_kernel(const float* __restrict__ src,
                                                         float* __restrict__ dst,
                                                         int nrows) {
    const int r = blockIdx.x * 4 + (threadIdx.x >> 6);
    if (r >= nrows) return;
    const int lane = threadIdx.x & 63;
    const int leaf = lane >> 3, j = lane & 7;
    const float* p = src + (size_t)r * D_DIM + leaf * 128 + j;

    float x[16];
    x[0] = p[0];
    float rs = __fmul_rn(x[0], x[0]);
#pragma unroll
    for (int i = 1; i < 16; i++) {
        x[i] = p[i * 8];
        rs = __fadd_rn(rs, __fmul_rn(x[i], x[i]));
    }
    rs = __fadd_rn(rs, __shfl_xor(rs, 1));
    rs = __fadd_rn(rs, __shfl_xor(rs, 2));
    rs = __fadd_rn(rs, __shfl_xor(rs, 4));
    rs = __fadd_rn(rs, __shfl_xor(rs, 8));
    rs = __fadd_rn(rs, __shfl_xor(rs, 16));
    rs = __fadd_rn(rs, __shfl_xor(rs, 32));

    const float nrm = fmaxf(__fsqrt_rn(rs), 1e-12f);
    float* q = dst + (size_t)r * D_DIM + leaf * 128 + j;
#pragma unroll
    for (int i = 0; i < 16; i++) q[i * 8] = __fdiv_rn(x[i], nrm);
}

// ---------------- panel-chain GEMM pass (128x256 tile, 8x16/thread) -------
// final_pass==0 : C = acc (raw P0);  ==1 : C = (C + acc) + bias, in place.
// Thread (tx,ty): rows m0+ty*8+i; cols n0 + g*64 + tx*4 + j  (g<4, j<4).
#define GT_M 128
#define GT_N 256
#define GT_K 16

__global__ __launch_bounds__(256) void gemm_pass_f32(const float* __restrict__ A,
                                                     const float* __restrict__ Bm,
                                                     const float* __restrict__ bias,
                                                     float* __restrict__ C,
                                                     int N, int Kd,
                                                     int kbeg, int kend,
                                                     int final_pass) {
    __shared__ float As[2][GT_K][GT_M + 4];
    __shared__ float Bs[2][GT_K][GT_N + 4];
    const int ntiles = N / GT_N;
    const int bn = blockIdx.x % ntiles;
    const int bm = blockIdx.x / ntiles;
    const int m0 = bm * GT_M, n0 = bn * GT_N;
    const int t = threadIdx.x;
    const int tx = t & 15, ty = t >> 4;
    const int lrA = t >> 1;
    const int lkA = (t & 1) * 8;

    const float* Arow = A + (size_t)(m0 + lrA) * Kd + lkA;
    const float* Brow = Bm + (size_t)(n0 + t) * Kd;

    float acc[8][16];
#pragma unroll
    for (int i = 0; i < 8; i++)
#pragma unroll
        for (int j = 0; j < 16; j++) acc[i][j] = 0.f;

    // prologue: stage first tile into buf 0
    {
        const float4 a0 = *(const float4*)(Arow + kbeg);
        const float4 a1 = *(const float4*)(Arow + kbeg + 4);
        const float4 b0 = *(const float4*)(Brow + kbeg);
        const float4 b1 = *(const float4*)(Brow + kbeg + 4);
        const float4 b2 = *(const float4*)(Brow + kbeg + 8);
        const float4 b3 = *(const float4*)(Brow + kbeg + 12);
        As[0][lkA + 0][lrA] = a0.x; As[0][lkA + 1][lrA] = a0.y;
        As[0][lkA + 2][lrA] = a0.z; As[0][lkA + 3][lrA] = a0.w;
        As[0][lkA + 4][lrA] = a1.x; As[0][lkA + 5][lrA] = a1.y;
        As[0][lkA + 6][lrA] = a1.z; As[0][lkA + 7][lrA] = a1.w;
        Bs[0][0][t] = b0.x;  Bs[0][1][t] = b0.y;  Bs[0][2][t] = b0.z;  Bs[0][3][t] = b0.w;
        Bs[0][4][t] = b1.x;  Bs[0][5][t] = b1.y;  Bs[0][6][t] = b1.z;  Bs[0][7][t] = b1.w;
        Bs[0][8][t] = b2.x;  Bs[0][9][t] = b2.y;  Bs[0][10][t] = b2.z; Bs[0][11][t] = b2.w;
        Bs[0][12][t] = b3.x; Bs[0][13][t] = b3.y; Bs[0][14][t] = b3.z; Bs[0][15][t] = b3.w;
    }
    __syncthreads();

    int cur = 0;
    for (int k0 = kbeg; k0 < kend; k0 += GT_K) {
        const bool has_next = (k0 + GT_K < kend);
        float4 na0, na1, nb0, nb1, nb2, nb3;
        if (has_next) {   // issue next-tile global loads before compute
            na0 = *(const float4*)(Arow + k0 + GT_K);
            na1 = *(const float4*)(Arow + k0 + GT_K + 4);
            nb0 = *(const float4*)(Brow + k0 + GT_K);
            nb1 = *(const float4*)(Brow + k0 + GT_K + 4);
            nb2 = *(const float4*)(Brow + k0 + GT_K + 8);
            nb3 = *(const float4*)(Brow + k0 + GT_K + 12);
        }
#pragma unroll
        for (int k = 0; k < GT_K; k++) {   // ascending k within panel
            const float4 av0 = *(const float4*)&As[cur][k][ty * 8];
            const float4 av1 = *(const float4*)&As[cur][k][ty * 8 + 4];
            const float4 bq0 = *(const float4*)&Bs[cur][k][tx * 4];
            const float4 bq1 = *(const float4*)&Bs[cur][k][64 + tx * 4];
            const float4 bq2 = *(const float4*)&Bs[cur][k][128 + tx * 4];
            const float4 bq3 = *(const float4*)&Bs[cur][k][192 + tx * 4];
            const float af[8] = {av0.x, av0.y, av0.z, av0.w, av1.x, av1.y, av1.z, av1.w};
            const float bf[16] = {bq0.x, bq0.y, bq0.z, bq0.w, bq1.x, bq1.y, bq1.z, bq1.w,
                                  bq2.x, bq2.y, bq2.z, bq2.w, bq3.x, bq3.y, bq3.z, bq3.w};
#pragma unroll
            for (int i = 0; i < 8; i++)
#pragma unroll
                for (int j = 0; j < 16; j++)
                    acc[i][j] = __fmaf_rn(af[i], bf[j], acc[i][j]);
        }
        if (has_next) {
            const int nxt = cur ^ 1;
            As[nxt][lkA + 0][lrA] = na0.x; As[nxt][lkA + 1][lrA] = na0.y;
            As[nxt][lkA + 2][lrA] = na0.z; As[nxt][lkA + 3][lrA] = na0.w;
            As[nxt][lkA + 4][lrA] = na1.x; As[nxt][lkA + 5][lrA] = na1.y;
            As[nxt][lkA + 6][lrA] = na1.z; As[nxt][lkA + 7][lrA] = na1.w;
            Bs[nxt][0][t] = nb0.x;  Bs[nxt][1][t] = nb0.y;  Bs[nxt][2][t] = nb0.z;  Bs[nxt][3][t] = nb0.w;
            Bs[nxt][4][t] = nb1.x;  Bs[nxt][5][t] = nb1.y;  Bs[nxt][6][t] = nb1.z;  Bs[nxt][7][t] = nb1.w;
            Bs[nxt][8][t] = nb2.x;  Bs[nxt][9][t] = nb2.y;  Bs[nxt][10][t] = nb2.z; Bs[nxt][11][t] = nb2.w;
            Bs[nxt][12][t] = nb3.x; Bs[nxt][13][t] = nb3.y; Bs[nxt][14][t] = nb3.z; Bs[nxt][15][t] = nb3.w;
            __syncthreads();
            cur = nxt;
        }
    }

    if (!final_pass) {
#pragma unroll
        for (int i = 0; i < 8; i++) {
            const size_t row = (size_t)(m0 + ty * 8 + i);
#pragma unroll
            for (int g = 0; g < 4; g++) {
                float4 c4;
                c4.x = acc[i][g * 4 + 0]; c4.y = acc[i][g * 4 + 1];
                c4.z = acc[i][g * 4 + 2]; c4.w = acc[i][g * 4 + 3];
                *(float4*)(C + row * (size_t)N + n0 + g * 64 + tx * 4) = c4;
            }
        }
    } else {
        float bj[16];
#pragma unroll
        for (int g = 0; g < 4; g++)
#pragma unroll
            for (int j = 0; j < 4; j++)
                bj[g * 4 + j] = bias ? bias[n0 + g * 64 + tx * 4 + j] : 0.f;
#pragma unroll
        for (int i = 0; i < 8; i++) {
            const size_t row = (size_t)(m0 + ty * 8 + i);
#pragma unroll
            for (int g = 0; g < 4; g++) {
                float* cp = C + row * (size_t)N + n0 + g * 64 + tx * 4;
                const float4 p0 = *(const float4*)cp;
                float4 c4;
                c4.x = __fadd_rn(__fadd_rn(p0.x, acc[i][g * 4 + 0]), bj[g * 4 + 0]);
                c4.y = __fadd_rn(__fadd_rn(p0.y, acc[i][g * 4 + 1]), bj[g * 4 + 1]);
                c4.z = __fadd_rn(__fadd_rn(p0.z, acc[i][g * 4 + 2]), bj[g * 4 + 2]);
                c4.w = __fadd_rn(__fadd_rn(p0.w, acc[i][g * 4 + 3]), bj[g * 4 + 3]);
                *(float4*)cp = c4;
            }
        }
    }
}

// ---------------- exact fp32 top-128 (ties -> lowest index) + softmax ------
// Register-resident keys; per-wave histograms; shfl wave scans. Element
// mapping i = t*16+j preserved -> identical tie ordering vs R18.
__device__ __forceinline__ unsigned f2key(float f) {
    unsigned u = __float_as_uint(f);
    return (u & 0x80000000u) ? ~u : (u | 0x80000000u);
}
__device__ __forceinline__ float key2f(unsigned k) {
    unsigned u = (k & 0x80000000u) ? (k & 0x7fffffffu) : ~k;
    return __uint_as_float(u);
}

__global__ __launch_bounds__(256) void topk32_kernel(const float* __restrict__ scores,
                                                     float* __restrict__ weights,
                                                     float* __restrict__ list) {
    __shared__ unsigned hist[4][256];
    __shared__ int wtot[4];
    __shared__ int wpre[4];
    __shared__ unsigned ubc[2];
    __shared__ float fred[8];

    const int r = blockIdx.x;
    const int t = threadIdx.x;
    const int lane = t & 63, wid = t >> 6;
    const float* srow = scores + (size_t)r * A_ATOMS + (size_t)t * 16;

    unsigned key[16];
#pragma unroll
    for (int c = 0; c < 4; c++) {
        const float4 f = ((const float4*)srow)[c];
        key[c * 4 + 0] = f2key(f.x); key[c * 4 + 1] = f2key(f.y);
        key[c * 4 + 2] = f2key(f.z); key[c * 4 + 3] = f2key(f.w);
    }

    // 4-pass radix select (8-bit digits, MSB first) for the 128th largest
    unsigned prefix = 0, remaining = K_TOP;
    for (int shift = 24; shift >= 0; shift -= 8) {
#pragma unroll
        for (int w = 0; w < 4; w++) hist[w][t] = 0u;
        __syncthreads();
#pragma unroll
        for (int j = 0; j < 16; j++) {
            const unsigned u = key[j];
            const bool isc = (shift == 24) || ((u >> (shift + 8)) == (prefix >> (shift + 8)));
            if (isc) atomicAdd(&hist[wid][(u >> shift) & 255u], 1u);
        }
        __syncthreads();
        const int c = (int)(hist[0][t] + hist[1][t] + hist[2][t] + hist[3][t]);
        // inclusive suffix scan within wave (bins ascend with lane)
        int sfx = c;
#pragma unroll
        for (int off = 1; off < 64; off <<= 1) {
            const int tv = __shfl_down(sfx, off, 64);
            sfx += (lane + off < 64) ? tv : 0;
        }
        if (lane == 0) wtot[wid] = sfx;
        __syncthreads();
        int addw = 0;
#pragma unroll
        for (int w = 0; w < 4; w++) if (w > wid) addw += wtot[w];
        sfx += addw;
        const int sfxn = sfx - c;
        if (sfx >= (int)remaining && sfxn < (int)remaining) {
            ubc[0] = prefix | ((unsigned)t << shift);
            ubc[1] = remaining - (unsigned)sfxn;
        }
        __syncthreads();
        prefix = ubc[0];
        remaining = ubc[1];
    }
    const unsigned Tkey = prefix;
    const int need = (int)remaining;

    // strict winners (bitmask); equals -> lowest `need` in index order
    int selmask = 0, myeq = 0;
#pragma unroll
    for (int j = 0; j < 16; j++) {
        if (key[j] > Tkey) selmask |= (1 << j);
        else if (key[j] == Tkey) myeq++;
    }
    int pre = myeq;   // inclusive ascending prefix within wave
#pragma unroll
    for (int off = 1; off < 64; off <<= 1) {
        const int tv = __shfl_up(pre, off, 64);
        pre += (lane >= off) ? tv : 0;
    }
    if (lane == 63) wpre[wid] = pre;
    __syncthreads();
    int basew = 0;
#pragma unroll
    for (int w = 0; w < 4; w++) if (w < wid) basew += wpre[w];
    int epos = basew + pre - myeq;   // exclusive prefix across block
#pragma unroll
    for (int j = 0; j < 16; j++) {
        if (key[j] == Tkey) { if (epos < need) selmask |= (1 << j); epos++; }
    }

    // fp32 softmax over selected (identical arithmetic to R18)
    float zmax = -3.4e38f;
#pragma unroll
    for (int j = 0; j < 16; j++)
        if (selmask & (1 << j)) zmax = fmaxf(zmax, __fdiv_rn(key2f(key[j]), 0.7f));
    for (int o = 32; o > 0; o >>= 1) zmax = fmaxf(zmax, __shfl_down(zmax, o, 64));
    if (lane == 0) fred[wid] = zmax;
    __syncthreads();
    if (t == 0) fred[4] = fmaxf(fmaxf(fred[0], fred[1]), fmaxf(fred[2], fred[3]));
    __syncthreads();
    const float zm = fred[4];

    float esum = 0.f;
#pragma unroll
    for (int j = 0; j < 16; j++)
        if (selmask & (1 << j)) esum += expf(__fdiv_rn(key2f(key[j]), 0.7f) - zm);
    for (int o = 32; o > 0; o >>= 1) esum += __shfl_down(esum, o, 64);
    if (lane == 0) fred[wid] = esum;
    __syncthreads();
    if (t == 0) fred[4] = fred[0] + fred[1] + fred[2] + fred[3];
    __syncthreads();
    const float S = fred[4];

    // dense weights (each thread owns contiguous 16 elements)
    float* wrow = weights + (size_t)r * A_ATOMS + (size_t)t * 16;
#pragma unroll
    for (int c = 0; c < 4; c++) {
        float4 w4;
        float wv[4];
#pragma unroll
        for (int j = 0; j < 4; j++) {
            const int jj = c * 4 + j;
            wv[j] = (selmask & (1 << jj))
                ? __fdiv_rn(expf(__fdiv_rn(key2f(key[jj]), 0.7f) - zm), S)
                : 0.f;
        }
        w4.x = wv[0]; w4.y = wv[1]; w4.z = wv[2]; w4.w = wv[3];
        ((float4*)wrow)[c] = w4;
    }

    // compact (idx, w) list in ascending atom-index order
    const int selcnt = __popc((unsigned)selmask);
    __syncthreads();   // protect wpre reuse
    int pre2 = selcnt;
#pragma unroll
    for (int off = 1; off < 64; off <<= 1) {
        const int tv = __shfl_up(pre2, off, 64);
        pre2 += (lane >= off) ? tv : 0;
    }
    if (lane == 63) wpre[wid] = pre2;
    __syncthreads();
    int basec = 0;
#pragma unroll
    for (int w = 0; w < 4; w++) if (w < wid) basec += wpre[w];
    int pos = basec + pre2 - selcnt;
    int* li = (int*)(list + (size_t)r * 256);
    float* lw = list + (size_t)r * 256 + 128;
#pragma unroll
    for (int j = 0; j < 16; j++) {
        if (selmask & (1 << j)) {
            const float w = __fdiv_rn(expf(__fdiv_rn(key2f(key[j]), 0.7f) - zm), S);
            if (pos < K_TOP) { li[pos] = t * 16 + j; lw[pos] = w; }
            pos++;
        }
    }
}

// ---------------- euc_raw[r] = sum_j w_j * atoms[idx_j] (ascending idx) -----
__global__ __launch_bounds__(256) void euc_gather_kernel(const float* __restrict__ atoms,
                                                         const float* __restrict__ list,
                                                         float* __restrict__ euc) {
    __shared__ int sidx[K_TOP];
    __shared__ float sw[K_TOP];
    const int r = blockIdx.x, t = threadIdx.x;
    if (t < K_TOP) {
        sidx[t] = ((const int*)list)[(size_t)r * 256 + t];
        sw[t] = list[(size_t)r * 256 + 128 + t];
    }
    __syncthreads();
    const float4* A4 = (const float4*)atoms;
    float4 acc = {0.f, 0.f, 0.f, 0.f};
#pragma unroll 4
    for (int j = 0; j < K_TOP; j++) {
        const float w = sw[j];
        const float4 a = A4[(size_t)sidx[j] * 256 + t];
        acc.x = __fmaf_rn(w, a.x, acc.x);
        acc.y = __fmaf_rn(w, a.y, acc.y);
        acc.z = __fmaf_rn(w, a.z, acc.z);
        acc.w = __fmaf_rn(w, a.w, acc.w);
    }
    ((float4*)euc)[(size_t)r * 256 + t] = acc;
}

// ---------------------------------------------------------------------------
extern "C" void kernel_launch(void* const* d_in, const int* in_sizes, int n_in,
                              void* d_out, int out_size, void* d_ws, size_t ws_size,
                              hipStream_t stream) {
    const float* base_raw = (const float*)d_in[0];
    const float* W        = (const float*)d_in[1];
    const float* bvec     = (const float*)d_in[2];
    const float* atoms    = (const float*)d_in[3];
    float* out = (float*)d_out;

    const size_t BD = (size_t)B_ROWS * D_DIM;   // 16,777,216
    const size_t BA = (size_t)B_ROWS * A_ATOMS; // 67,108,864
    float* base_emb = out;
    float* weights  = out + BD;
    float* scores   = out + BD + BA;
    float* euc_raw  = out + BD + 2 * BA;
    float* euc_vec  = out + 2 * BD + 2 * BA;

    float* a_norm = base_emb;  // scratch: A*D = 4.2M floats <= BD
    float* q      = weights;   // scratch: B*D floats <= BA
    float* list   = euc_vec;   // scratch: B*256 floats <= BD

    const int grid_q = (B_ROWS / GT_M) * (D_DIM / GT_N);
    const int grid_s = (B_ROWS / GT_M) * (A_ATOMS / GT_N);

    // 1. a_norm = l2norm_np(atoms)
    rownorm_np_kernel<<<A_ATOMS / 4, 256, 0, stream>>>(atoms, a_norm, A_ATOMS);
    // 2. q_raw = base_raw @ W^T + b   (two-pass {512,512} flat chains)
    gemm_pass_f32<<<grid_q, 256, 0, stream>>>(base_raw, W, nullptr, q,
                                              D_DIM, D_DIM, 0, KC_PANEL, 0);
    gemm_pass_f32<<<grid_q, 256, 0, stream>>>(base_raw, W, bvec, q,
                                              D_DIM, D_DIM, KC_PANEL, D_DIM, 1);
    // 3. q = l2norm_np(q_raw) in place
    rownorm_np_kernel<<<B_ROWS / 4, 256, 0, stream>>>(q, q, B_ROWS);
    // 4. scores = q @ a_norm^T        (two-pass {512,512} flat chains)
    gemm_pass_f32<<<grid_s, 256, 0, stream>>>(q, a_norm, nullptr, scores,
                                              A_ATOMS, D_DIM, 0, KC_PANEL, 0);
    gemm_pass_f32<<<grid_s, 256, 0, stream>>>(q, a_norm, nullptr, scores,
                                              A_ATOMS, D_DIM, KC_PANEL, D_DIM, 1);
    // 5. exact fp32 top-128 (stable ties) + fp32 softmax -> weights + list
    topk32_kernel<<<B_ROWS, 256, 0, stream>>>(scores, weights, list);
    // 6. euc_raw = weights @ atoms (sparse gather, ascending index chain)
    euc_gather_kernel<<<B_ROWS, 256, 0, stream>>>(atoms, list, euc_raw);
    // 7. euc_vec = l2norm_np(euc_raw)
    rownorm_np_kernel<<<B_ROWS / 4, 256, 0, stream>>>(euc_raw, euc_vec, B_ROWS);
    // 8. base_emb = l2norm_np(base_raw)  (last: frees a_norm aliasing)
    rownorm_np_kernel<<<B_ROWS / 4, 256, 0, stream>>>(base_raw, base_emb, B_ROWS);
}

// Round 23
// 2988.475 us; speedup vs baseline: 2.6987x; 1.0439x over previous
//
#include <hip/hip_runtime.h>
#include <hip/hip_bf16.h>

// ---------------------------------------------------------------------------
// H_ACS_Encoder: B=16384, D=1024, A=4096, topk=128, T=0.7
// Outputs (flat): base_emb[B,D], weights[B,A], scores[B,A], euc_raw[B,D], euc_vec[B,D]
//
// ROUND 23 = R21 GEMM (validated best: 128x128, 8x8/thread, single-buffer
// LDS + reg prefetch, two-pass {512,512}, VGPR108 @ 4 waves/SIMD, 852us/pass)
//          + R22 topk (register-resident keys, per-wave hists, shfl scans,
//            ~250us). R22's 128x256 GEMM regressed (VGPR144 -> 3 waves,
//            VALU 55%) and is reverted.
//
// Scratch aliasing (no d_ws):
//   a_norm (A*D f32) -> base_emb region (base_emb written LAST)
//   q      (B*D f32) -> weights region  (dead before weights write)
//   list   (B*256)   -> euc_vec region  (dead before final norm)
// ---------------------------------------------------------------------------

#define B_ROWS 16384
#define D_DIM  1024
#define A_ATOMS 4096
#define K_TOP  128

#define KC_PANEL 512   // validated R18: AOCL/BLIS KC=512 -> panels {512,512}

// ---------------- numpy-pairwise row l2-normalize (1 wave/row, 4 rows/blk) --
__global__ __launch_bounds__(256) void rownorm_np_kernel(const float* __restrict__ src,
                                                         float* __restrict__ dst,
                                                         int nrows) {
    const int r = blockIdx.x * 4 + (threadIdx.x >> 6);
    if (r >= nrows) return;
    const int lane = threadIdx.x & 63;
    const int leaf = lane >> 3, j = lane & 7;
    const float* p = src + (size_t)r * D_DIM + leaf * 128 + j;

    float x[16];
    x[0] = p[0];
    float rs = __fmul_rn(x[0], x[0]);
#pragma unroll
    for (int i = 1; i < 16; i++) {
        x[i] = p[i * 8];
        rs = __fadd_rn(rs, __fmul_rn(x[i], x[i]));
    }
    rs = __fadd_rn(rs, __shfl_xor(rs, 1));
    rs = __fadd_rn(rs, __shfl_xor(rs, 2));
    rs = __fadd_rn(rs, __shfl_xor(rs, 4));
    rs = __fadd_rn(rs, __shfl_xor(rs, 8));
    rs = __fadd_rn(rs, __shfl_xor(rs, 16));
    rs = __fadd_rn(rs, __shfl_xor(rs, 32));

    const float nrm = fmaxf(__fsqrt_rn(rs), 1e-12f);
    float* q = dst + (size_t)r * D_DIM + leaf * 128 + j;
#pragma unroll
    for (int i = 0; i < 16; i++) q[i * 8] = __fdiv_rn(x[i], nrm);
}

// ---------------- panel-chain GEMM pass: acc = flat chain over [kbeg,kend) --
// final_pass==0 : C[m][n] = acc                      (raw P0)
// final_pass==1 : C[m][n] = (C[m][n] + acc) + bias   (fold + bias, in place)
// Thread (tx,ty): rows ty*8+{0..7}, cols tx*4+{0..3} and 64+tx*4+{0..3}.
#define GT_M 128
#define GT_N 128
#define GT_K 16

__global__ __launch_bounds__(256) void gemm_pass_f32(const float* __restrict__ A,
                                                     const float* __restrict__ Bm,
                                                     const float* __restrict__ bias,
                                                     float* __restrict__ C,
                                                     int N, int Kd,
                                                     int kbeg, int kend,
                                                     int final_pass) {
    __shared__ float As[GT_K][GT_M + 4];
    __shared__ float Bs[GT_K][GT_N + 4];
    const int ntiles = N / GT_N;
    const int bn = blockIdx.x % ntiles;
    const int bm = blockIdx.x / ntiles;
    const int m0 = bm * GT_M, n0 = bn * GT_N;
    const int t = threadIdx.x;
    const int tx = t & 15, ty = t >> 4;
    const int lr = t >> 1;
    const int lk = (t & 1) * 8;

    const float* Arow = A + (size_t)(m0 + lr) * Kd + lk;
    const float* Brow = Bm + (size_t)(n0 + lr) * Kd + lk;

    float acc[8][8];
#pragma unroll
    for (int i = 0; i < 8; i++)
#pragma unroll
        for (int j = 0; j < 8; j++) acc[i][j] = 0.f;

    // prologue: stage first tile
    {
        const float4 a0 = *(const float4*)(Arow + kbeg);
        const float4 a1 = *(const float4*)(Arow + kbeg + 4);
        const float4 b0 = *(const float4*)(Brow + kbeg);
        const float4 b1 = *(const float4*)(Brow + kbeg + 4);
        As[lk + 0][lr] = a0.x; As[lk + 1][lr] = a0.y; As[lk + 2][lr] = a0.z; As[lk + 3][lr] = a0.w;
        As[lk + 4][lr] = a1.x; As[lk + 5][lr] = a1.y; As[lk + 6][lr] = a1.z; As[lk + 7][lr] = a1.w;
        Bs[lk + 0][lr] = b0.x; Bs[lk + 1][lr] = b0.y; Bs[lk + 2][lr] = b0.z; Bs[lk + 3][lr] = b0.w;
        Bs[lk + 4][lr] = b1.x; Bs[lk + 5][lr] = b1.y; Bs[lk + 6][lr] = b1.z; Bs[lk + 7][lr] = b1.w;
    }
    __syncthreads();

    for (int k0 = kbeg; k0 < kend; k0 += GT_K) {
        const bool has_next = (k0 + GT_K < kend);
        float4 na0, na1, nb0, nb1;
        if (has_next) {               // issue next-tile loads BEFORE compute
            na0 = *(const float4*)(Arow + k0 + GT_K);
            na1 = *(const float4*)(Arow + k0 + GT_K + 4);
            nb0 = *(const float4*)(Brow + k0 + GT_K);
            nb1 = *(const float4*)(Brow + k0 + GT_K + 4);
        }
#pragma unroll
        for (int k = 0; k < GT_K; k++) {   // ascending k within panel
            const float4 av0 = *(const float4*)&As[k][ty * 8];
            const float4 av1 = *(const float4*)&As[k][ty * 8 + 4];
            const float4 bv0 = *(const float4*)&Bs[k][tx * 4];
            const float4 bv1 = *(const float4*)&Bs[k][64 + tx * 4];
            const float af[8] = {av0.x, av0.y, av0.z, av0.w, av1.x, av1.y, av1.z, av1.w};
            const float bf[8] = {bv0.x, bv0.y, bv0.z, bv0.w, bv1.x, bv1.y, bv1.z, bv1.w};
#pragma unroll
            for (int i = 0; i < 8; i++)
#pragma unroll
                for (int j = 0; j < 8; j++)
                    acc[i][j] = __fmaf_rn(af[i], bf[j], acc[i][j]);
        }
        if (has_next) {
            __syncthreads();   // all reads of current tile complete
            As[lk + 0][lr] = na0.x; As[lk + 1][lr] = na0.y; As[lk + 2][lr] = na0.z; As[lk + 3][lr] = na0.w;
            As[lk + 4][lr] = na1.x; As[lk + 5][lr] = na1.y; As[lk + 6][lr] = na1.z; As[lk + 7][lr] = na1.w;
            Bs[lk + 0][lr] = nb0.x; Bs[lk + 1][lr] = nb0.y; Bs[lk + 2][lr] = nb0.z; Bs[lk + 3][lr] = nb0.w;
            Bs[lk + 4][lr] = nb1.x; Bs[lk + 5][lr] = nb1.y; Bs[lk + 6][lr] = nb1.z; Bs[lk + 7][lr] = nb1.w;
            __syncthreads();
        }
    }

    if (!final_pass) {
        // raw P0 chain out
#pragma unroll
        for (int i = 0; i < 8; i++) {
            const size_t row = (size_t)(m0 + ty * 8 + i);
            float4 c0, c1;
            c0.x = acc[i][0]; c0.y = acc[i][1]; c0.z = acc[i][2]; c0.w = acc[i][3];
            c1.x = acc[i][4]; c1.y = acc[i][5]; c1.z = acc[i][6]; c1.w = acc[i][7];
            *(float4*)(C + row * (size_t)N + n0 + tx * 4) = c0;
            *(float4*)(C + row * (size_t)N + n0 + 64 + tx * 4) = c1;
        }
    } else {
        float bj[8];
#pragma unroll
        for (int j = 0; j < 4; j++) {
            bj[j]     = bias ? bias[n0 + tx * 4 + j]      : 0.f;
            bj[4 + j] = bias ? bias[n0 + 64 + tx * 4 + j] : 0.f;
        }
#pragma unroll
        for (int i = 0; i < 8; i++) {
            const size_t row = (size_t)(m0 + ty * 8 + i);
            float* cp0 = C + row * (size_t)N + n0 + tx * 4;
            float* cp1 = C + row * (size_t)N + n0 + 64 + tx * 4;
            const float4 p0a = *(const float4*)cp0;
            const float4 p0b = *(const float4*)cp1;
            float4 c0, c1;
            c0.x = __fadd_rn(__fadd_rn(p0a.x, acc[i][0]), bj[0]);
            c0.y = __fadd_rn(__fadd_rn(p0a.y, acc[i][1]), bj[1]);
            c0.z = __fadd_rn(__fadd_rn(p0a.z, acc[i][2]), bj[2]);
            c0.w = __fadd_rn(__fadd_rn(p0a.w, acc[i][3]), bj[3]);
            c1.x = __fadd_rn(__fadd_rn(p0b.x, acc[i][4]), bj[4]);
            c1.y = __fadd_rn(__fadd_rn(p0b.y, acc[i][5]), bj[5]);
            c1.z = __fadd_rn(__fadd_rn(p0b.z, acc[i][6]), bj[6]);
            c1.w = __fadd_rn(__fadd_rn(p0b.w, acc[i][7]), bj[7]);
            *(float4*)cp0 = c0;
            *(float4*)cp1 = c1;
        }
    }
}

// ---------------- exact fp32 top-128 (ties -> lowest index) + softmax ------
// Register-resident keys; per-wave histograms; shfl wave scans. Element
// mapping i = t*16+j preserved -> identical tie ordering vs R18.
__device__ __forceinline__ unsigned f2key(float f) {
    unsigned u = __float_as_uint(f);
    return (u & 0x80000000u) ? ~u : (u | 0x80000000u);
}
__device__ __forceinline__ float key2f(unsigned k) {
    unsigned u = (k & 0x80000000u) ? (k & 0x7fffffffu) : ~k;
    return __uint_as_float(u);
}

__global__ __launch_bounds__(256) void topk32_kernel(const float* __restrict__ scores,
                                                     float* __restrict__ weights,
                                                     float* __restrict__ list) {
    __shared__ unsigned hist[4][256];
    __shared__ int wtot[4];
    __shared__ int wpre[4];
    __shared__ unsigned ubc[2];
    __shared__ float fred[8];

    const int r = blockIdx.x;
    const int t = threadIdx.x;
    const int lane = t & 63, wid = t >> 6;
    const float* srow = scores + (size_t)r * A_ATOMS + (size_t)t * 16;

    unsigned key[16];
#pragma unroll
    for (int c = 0; c < 4; c++) {
        const float4 f = ((const float4*)srow)[c];
        key[c * 4 + 0] = f2key(f.x); key[c * 4 + 1] = f2key(f.y);
        key[c * 4 + 2] = f2key(f.z); key[c * 4 + 3] = f2key(f.w);
    }

    // 4-pass radix select (8-bit digits, MSB first) for the 128th largest
    unsigned prefix = 0, remaining = K_TOP;
    for (int shift = 24; shift >= 0; shift -= 8) {
#pragma unroll
        for (int w = 0; w < 4; w++) hist[w][t] = 0u;
        __syncthreads();
#pragma unroll
        for (int j = 0; j < 16; j++) {
            const unsigned u = key[j];
            const bool isc = (shift == 24) || ((u >> (shift + 8)) == (prefix >> (shift + 8)));
            if (isc) atomicAdd(&hist[wid][(u >> shift) & 255u], 1u);
        }
        __syncthreads();
        const int c = (int)(hist[0][t] + hist[1][t] + hist[2][t] + hist[3][t]);
        // inclusive suffix scan within wave (bins ascend with lane)
        int sfx = c;
#pragma unroll
        for (int off = 1; off < 64; off <<= 1) {
            const int tv = __shfl_down(sfx, off, 64);
            sfx += (lane + off < 64) ? tv : 0;
        }
        if (lane == 0) wtot[wid] = sfx;
        __syncthreads();
        int addw = 0;
#pragma unroll
        for (int w = 0; w < 4; w++) if (w > wid) addw += wtot[w];
        sfx += addw;
        const int sfxn = sfx - c;
        if (sfx >= (int)remaining && sfxn < (int)remaining) {
            ubc[0] = prefix | ((unsigned)t << shift);
            ubc[1] = remaining - (unsigned)sfxn;
        }
        __syncthreads();
        prefix = ubc[0];
        remaining = ubc[1];
    }
    const unsigned Tkey = prefix;
    const int need = (int)remaining;

    // strict winners (bitmask); equals -> lowest `need` in index order
    int selmask = 0, myeq = 0;
#pragma unroll
    for (int j = 0; j < 16; j++) {
        if (key[j] > Tkey) selmask |= (1 << j);
        else if (key[j] == Tkey) myeq++;
    }
    int pre = myeq;   // inclusive ascending prefix within wave
#pragma unroll
    for (int off = 1; off < 64; off <<= 1) {
        const int tv = __shfl_up(pre, off, 64);
        pre += (lane >= off) ? tv : 0;
    }
    if (lane == 63) wpre[wid] = pre;
    __syncthreads();
    int basew = 0;
#pragma unroll
    for (int w = 0; w < 4; w++) if (w < wid) basew += wpre[w];
    int epos = basew + pre - myeq;   // exclusive prefix across block
#pragma unroll
    for (int j = 0; j < 16; j++) {
        if (key[j] == Tkey) { if (epos < need) selmask |= (1 << j); epos++; }
    }

    // fp32 softmax over selected (identical arithmetic to R18)
    float zmax = -3.4e38f;
#pragma unroll
    for (int j = 0; j < 16; j++)
        if (selmask & (1 << j)) zmax = fmaxf(zmax, __fdiv_rn(key2f(key[j]), 0.7f));
    for (int o = 32; o > 0; o >>= 1) zmax = fmaxf(zmax, __shfl_down(zmax, o, 64));
    if (lane == 0) fred[wid] = zmax;
    __syncthreads();
    if (t == 0) fred[4] = fmaxf(fmaxf(fred[0], fred[1]), fmaxf(fred[2], fred[3]));
    __syncthreads();
    const float zm = fred[4];

    float esum = 0.f;
#pragma unroll
    for (int j = 0; j < 16; j++)
        if (selmask & (1 << j)) esum += expf(__fdiv_rn(key2f(key[j]), 0.7f) - zm);
    for (int o = 32; o > 0; o >>= 1) esum += __shfl_down(esum, o, 64);
    if (lane == 0) fred[wid] = esum;
    __syncthreads();
    if (t == 0) fred[4] = fred[0] + fred[1] + fred[2] + fred[3];
    __syncthreads();
    const float S = fred[4];

    // dense weights (each thread owns contiguous 16 elements)
    float* wrow = weights + (size_t)r * A_ATOMS + (size_t)t * 16;
#pragma unroll
    for (int c = 0; c < 4; c++) {
        float4 w4;
        float wv[4];
#pragma unroll
        for (int j = 0; j < 4; j++) {
            const int jj = c * 4 + j;
            wv[j] = (selmask & (1 << jj))
                ? __fdiv_rn(expf(__fdiv_rn(key2f(key[jj]), 0.7f) - zm), S)
                : 0.f;
        }
        w4.x = wv[0]; w4.y = wv[1]; w4.z = wv[2]; w4.w = wv[3];
        ((float4*)wrow)[c] = w4;
    }

    // compact (idx, w) list in ascending atom-index order
    const int selcnt = __popc((unsigned)selmask);
    __syncthreads();   // protect wpre reuse
    int pre2 = selcnt;
#pragma unroll
    for (int off = 1; off < 64; off <<= 1) {
        const int tv = __shfl_up(pre2, off, 64);
        pre2 += (lane >= off) ? tv : 0;
    }
    if (lane == 63) wpre[wid] = pre2;
    __syncthreads();
    int basec = 0;
#pragma unroll
    for (int w = 0; w < 4; w++) if (w < wid) basec += wpre[w];
    int pos = basec + pre2 - selcnt;
    int* li = (int*)(list + (size_t)r * 256);
    float* lw = list + (size_t)r * 256 + 128;
#pragma unroll
    for (int j = 0; j < 16; j++) {
        if (selmask & (1 << j)) {
            const float w = __fdiv_rn(expf(__fdiv_rn(key2f(key[j]), 0.7f) - zm), S);
            if (pos < K_TOP) { li[pos] = t * 16 + j; lw[pos] = w; }
            pos++;
        }
    }
}

// ---------------- euc_raw[r] = sum_j w_j * atoms[idx_j] (ascending idx) -----
__global__ __launch_bounds__(256) void euc_gather_kernel(const float* __restrict__ atoms,
                                                         const float* __restrict__ list,
                                                         float* __restrict__ euc) {
    __shared__ int sidx[K_TOP];
    __shared__ float sw[K_TOP];
    const int r = blockIdx.x, t = threadIdx.x;
    if (t < K_TOP) {
        sidx[t] = ((const int*)list)[(size_t)r * 256 + t];
        sw[t] = list[(size_t)r * 256 + 128 + t];
    }
    __syncthreads();
    const float4* A4 = (const float4*)atoms;
    float4 acc = {0.f, 0.f, 0.f, 0.f};
#pragma unroll 4
    for (int j = 0; j < K_TOP; j++) {
        const float w = sw[j];
        const float4 a = A4[(size_t)sidx[j] * 256 + t];
        acc.x = __fmaf_rn(w, a.x, acc.x);
        acc.y = __fmaf_rn(w, a.y, acc.y);
        acc.z = __fmaf_rn(w, a.z, acc.z);
        acc.w = __fmaf_rn(w, a.w, acc.w);
    }
    ((float4*)euc)[(size_t)r * 256 + t] = acc;
}

// ---------------------------------------------------------------------------
extern "C" void kernel_launch(void* const* d_in, const int* in_sizes, int n_in,
                              void* d_out, int out_size, void* d_ws, size_t ws_size,
                              hipStream_t stream) {
    const float* base_raw = (const float*)d_in[0];
    const float* W        = (const float*)d_in[1];
    const float* bvec     = (const float*)d_in[2];
    const float* atoms    = (const float*)d_in[3];
    float* out = (float*)d_out;

    const size_t BD = (size_t)B_ROWS * D_DIM;   // 16,777,216
    const size_t BA = (size_t)B_ROWS * A_ATOMS; // 67,108,864
    float* base_emb = out;
    float* weights  = out + BD;
    float* scores   = out + BD + BA;
    float* euc_raw  = out + BD + 2 * BA;
    float* euc_vec  = out + 2 * BD + 2 * BA;

    float* a_norm = base_emb;  // scratch: A*D = 4.2M floats <= BD
    float* q      = weights;   // scratch: B*D floats <= BA
    float* list   = euc_vec;   // scratch: B*256 floats <= BD

    const int grid_q = (B_ROWS / GT_M) * (D_DIM / GT_N);
    const int grid_s = (B_ROWS / GT_M) * (A_ATOMS / GT_N);

    // 1. a_norm = l2norm_np(atoms)
    rownorm_np_kernel<<<A_ATOMS / 4, 256, 0, stream>>>(atoms, a_norm, A_ATOMS);
    // 2. q_raw = base_raw @ W^T + b   (two-pass {512,512} flat chains)
    gemm_pass_f32<<<grid_q, 256, 0, stream>>>(base_raw, W, nullptr, q,
                                              D_DIM, D_DIM, 0, KC_PANEL, 0);
    gemm_pass_f32<<<grid_q, 256, 0, stream>>>(base_raw, W, bvec, q,
                                              D_DIM, D_DIM, KC_PANEL, D_DIM, 1);
    // 3. q = l2norm_np(q_raw) in place
    rownorm_np_kernel<<<B_ROWS / 4, 256, 0, stream>>>(q, q, B_ROWS);
    // 4. scores = q @ a_norm^T        (two-pass {512,512} flat chains)
    gemm_pass_f32<<<grid_s, 256, 0, stream>>>(q, a_norm, nullptr, scores,
                                              A_ATOMS, D_DIM, 0, KC_PANEL, 0);
    gemm_pass_f32<<<grid_s, 256, 0, stream>>>(q, a_norm, nullptr, scores,
                                              A_ATOMS, D_DIM, KC_PANEL, D_DIM, 1);
    // 5. exact fp32 top-128 (stable ties) + fp32 softmax -> weights + list
    topk32_kernel<<<B_ROWS, 256, 0, stream>>>(scores, weights, list);
    // 6. euc_raw = weights @ atoms (sparse gather, ascending index chain)
    euc_gather_kernel<<<B_ROWS, 256, 0, stream>>>(atoms, list, euc_raw);
    // 7. euc_vec = l2norm_np(euc_raw)
    rownorm_np_kernel<<<B_ROWS / 4, 256, 0, stream>>>(euc_raw, euc_vec, B_ROWS);
    // 8. base_emb = l2norm_np(base_raw)  (last: frees a_norm aliasing)
    rownorm_np_kernel<<<B_ROWS / 4, 256, 0, stream>>>(base_raw, base_emb, B_ROWS);
}